// Round 11
// baseline (228.304 us; speedup 1.0000x reference)
//
#include <hip/hip_runtime.h>

typedef short s16x8 __attribute__((ext_vector_type(8)));
typedef float f32x4 __attribute__((ext_vector_type(4)));

__device__ inline unsigned short bf16_rn(float f) {
  unsigned int u = __float_as_uint(f);
  return (unsigned short)((u + 0x7FFFu + ((u >> 16) & 1u)) >> 16);
}
__device__ inline float bf16f(unsigned short h) {
  return __uint_as_float(((unsigned int)h) << 16);
}

// lexicographic (d,k) compare-swap / min helpers for the top-4 merge
__device__ __forceinline__ void lexswap(float& da, int& ka, float& db, int& kb) {
  bool sw = (db < da) || (db == da && kb < ka);
  float nd = sw ? db : da, xd = sw ? da : db;
  int nk = sw ? kb : ka, xk = sw ? ka : kb;
  da = nd; db = xd; ka = nk; kb = xk;
}
__device__ __forceinline__ void lexmin2(float& da, int& ka, float ob, int okb) {
  bool sw = (ob < da) || (ob == da && okb < ka);
  da = sw ? ob : da; ka = sw ? okb : ka;
}

// ---------------------------------------------------------------------------
// Kernel 1: codebook -> ROW-MAJOR hi-only bf16 image [1024][128] (256 KB,
// permanently L2-resident) + exact fp32 norms. No tiling, no swizzle —
// the main kernel reads B-fragments directly from L1/L2, not via LDS.
// ---------------------------------------------------------------------------
__global__ __launch_bounds__(64) void vq_convert_cb(const float* __restrict__ cb,
                                                    unsigned short* __restrict__ cbimg,
                                                    float* __restrict__ cbn) {
  int k = blockIdx.x * 64 + threadIdx.x;  // 0..1023
  const float* row = cb + (size_t)k * 128;
  unsigned short* dst = cbimg + (size_t)k * 128;
  float nrm = 0.f;
#pragma unroll
  for (int c = 0; c < 16; ++c) {
    float4 a = *(const float4*)(row + c * 8);
    float4 b = *(const float4*)(row + c * 8 + 4);
    float v[8] = {a.x, a.y, a.z, a.w, b.x, b.y, b.z, b.w};
    unsigned int hw[4];
#pragma unroll
    for (int i = 0; i < 4; ++i) {
      unsigned short h0 = bf16_rn(v[2 * i]), h1 = bf16_rn(v[2 * i + 1]);
      hw[i] = (unsigned)h0 | ((unsigned)h1 << 16);
      nrm += v[2 * i] * v[2 * i] + v[2 * i + 1] * v[2 * i + 1];
    }
    *(uint4*)(dst + c * 8) = make_uint4(hw[0], hw[1], hw[2], hw[3]);
  }
  cbn[k] = nrm;
}

// ---------------------------------------------------------------------------
// Kernel 2: fused main — BARRIER-FREE main loop. 512 blocks x 512 thr
// (8 waves, (512,4)), 16 tokens/wave. R10's counters showed a ~40 µs
// pure-idle hole (pipes sum 60 < dur 99.5): the 16 per-phase barrier+vmcnt
// convoys. Fix: B-fragments are read DIRECTLY from the 256 KB L2-resident
// hi-image via per-lane global_load_dwordx4 (16 B each) — no LDS staging,
// no double-buffer, no in-loop __syncthreads. Waves free-run/self-stagger
// so L2-read, MFMA, and top-2 VALU of different waves overlap. 2-pass
// hi-only MFMA (absmax-proven) + R1's cheap unpacked top-2 + top-4
// butterfly + exact fp32 rescore of 4 candidates. LDS = 5.3 KB total.
// ---------------------------------------------------------------------------
__global__ __launch_bounds__(512, 4) void vq_main(
    const float* __restrict__ xg, const float* __restrict__ cb,
    const unsigned short* __restrict__ cbimg, const float* __restrict__ cbn,
    float* __restrict__ xq, float* __restrict__ loss) {
  __shared__ float sNorm[1024];
  __shared__ int sKa[128], sKb[128];  // k1|k2<<16, k3|k4<<16 per token
  __shared__ float sLoss[8];
  const int tid = threadIdx.x;
  const int wave = tid >> 6, lane = tid & 63;
  const int i0 = lane & 15, q = lane >> 4;
  const int tokW = blockIdx.x * 128 + wave * 16;

  // ---- stage codebook norms into LDS (4 KB, 512 thr x float2) ----
  *(float2*)&sNorm[tid * 2] = *(const float2*)(cbn + tid * 2);

  // ---- load own 16 tokens, split fp32 -> bf16 hi + bf16 lo in-register ----
  s16x8 ahi[4], alo[4];
#pragma unroll
  for (int kf = 0; kf < 4; ++kf) {
    const float* p = xg + (size_t)(tokW + i0) * 128 + kf * 32 + q * 8;
    float4 a = *(const float4*)p, b = *(const float4*)(p + 4);
    float v[8] = {a.x, a.y, a.z, a.w, b.x, b.y, b.z, b.w};
    s16x8 h, l;
#pragma unroll
    for (int j = 0; j < 8; ++j) {
      unsigned short hh = bf16_rn(v[j]);
      float rr = v[j] - bf16f(hh);
      h[j] = (short)hh;
      l[j] = (short)bf16_rn(rr);
    }
    ahi[kf] = h;
    alo[kf] = l;
  }

  // per-lane B base: row i0 (within 16-row group), dim chunk q
  const char* bbase = (const char*)cbimg + i0 * 256 + q * 16;

  float d1[4], d2[4];
  int k1[4], k2[4];
#pragma unroll
  for (int g = 0; g < 4; ++g) {
    d1[g] = 3.4e38f; d2[g] = 3.4e38f; k1[g] = 0; k2[g] = 0;
  }
  __syncthreads();  // sNorm visible; the ONLY barrier before the tail

  for (int t = 0; t < 16; ++t) {
    const char* bt = bbase + t * 16384;  // 64 codes x 256 B per t-step
    f32x4 acc[4];
#pragma unroll
    for (int c = 0; c < 4; ++c) acc[c] = (f32x4){0.f, 0.f, 0.f, 0.f};

#pragma unroll
    for (int ks = 0; ks < 4; ++ks) {
      // batched direct loads: 4 x global_load_dwordx4 from L1/L2 (16 B/lane;
      // lane (i0,q) reads row c*16+i0, bytes (ks*4+q)*16 — contiguous 64 B
      // per row across the q-quad)
      s16x8 bhi[4];
#pragma unroll
      for (int c = 0; c < 4; ++c)
        bhi[c] = *(const s16x8*)(bt + c * 4096 + ks * 64);
      __builtin_amdgcn_s_setprio(1);
#pragma unroll
      for (int c = 0; c < 4; ++c)
        acc[c] = __builtin_amdgcn_mfma_f32_16x16x32_bf16(ahi[ks], bhi[c], acc[c], 0, 0, 0);
#pragma unroll
      for (int c = 0; c < 4; ++c)
        acc[c] = __builtin_amdgcn_mfma_f32_16x16x32_bf16(alo[ks], bhi[c], acc[c], 0, 0, 0);
      __builtin_amdgcn_s_setprio(0);
    }
    // ---- approx top-2 update (R1's proven cheap form);
    //      candidates arrive k-ascending, strict < keeps first-min ----
#pragma unroll
    for (int c = 0; c < 4; ++c) {
      int kc = t * 64 + c * 16 + i0;
      float cn = sNorm[kc];
#pragma unroll
      for (int g = 0; g < 4; ++g) {
        float dd = fmaf(-2.f, acc[c][g], cn);
        bool w = dd < d1[g];
        float ld = w ? d1[g] : dd;
        int lk = w ? k1[g] : kc;
        d1[g] = w ? dd : d1[g];
        k1[g] = w ? kc : k1[g];
        bool w2 = ld < d2[g];
        d2[g] = w2 ? ld : d2[g];
        k2[g] = w2 ? lk : k2[g];
      }
    }
    // NO barrier — waves free-run
  }

  // ---- extend to 4-deep sorted lists (pads at +inf) ----
  int k3[4], k4[4];
  float d3[4], d4[4];
#pragma unroll
  for (int g = 0; g < 4; ++g) {
    d3[g] = 3.4e38f; d4[g] = 3.4e38f; k3[g] = 0; k4[g] = 0;
  }

  // ---- butterfly top-4 merge across the 16 i0-lanes (lex d,k) ----
#pragma unroll
  for (int off = 1; off < 16; off <<= 1) {
#pragma unroll
    for (int g = 0; g < 4; ++g) {
      float ob0 = __shfl_xor(d1[g], off), ob1 = __shfl_xor(d2[g], off);
      float ob2 = __shfl_xor(d3[g], off), ob3 = __shfl_xor(d4[g], off);
      int ok0 = __shfl_xor(k1[g], off), ok1 = __shfl_xor(k2[g], off);
      int ok2 = __shfl_xor(k3[g], off), ok3 = __shfl_xor(k4[g], off);
      float m0 = d1[g], m1 = d2[g], m2 = d3[g], m3 = d4[g];
      int n0 = k1[g], n1 = k2[g], n2 = k3[g], n3 = k4[g];
      lexmin2(m0, n0, ob3, ok3);  // a_i vs b_{3-i} -> 4 smallest of union
      lexmin2(m1, n1, ob2, ok2);
      lexmin2(m2, n2, ob1, ok1);
      lexmin2(m3, n3, ob0, ok0);
      lexswap(m0, n0, m2, n2);    // sort the 4
      lexswap(m1, n1, m3, n3);
      lexswap(m0, n0, m1, n1);
      lexswap(m2, n2, m3, n3);
      lexswap(m1, n1, m2, n2);
      d1[g] = m0; d2[g] = m1; d3[g] = m2; d4[g] = m3;
      k1[g] = n0; k2[g] = n1; k3[g] = n2; k4[g] = n3;
    }
  }

  if (i0 == 0) {
#pragma unroll
    for (int g = 0; g < 4; ++g) {
      sKa[wave * 16 + q * 4 + g] = k1[g] | (k2[g] << 16);
      sKb[wave * 16 + q * 4 + g] = k3[g] | (k4[g] << 16);
    }
  }
  __syncthreads();

  // ---- epilogue: exact fp32 rescore of the 4-candidate union,
  //      winner re-read (L2-hot) + coalesced xq store; block-local loss ----
  float lacc = 0.f;
  {
    int ltok = wave * 16 + i0;
    int a = sKa[ltok], b = sKb[ltok];
    int ca = a & 0xFFFF, cb2 = (a >> 16) & 0xFFFF;
    int cc = b & 0xFFFF, cd = (b >> 16) & 0xFFFF;
    size_t token = (size_t)tokW + i0;
    float s1 = 0.f, s2 = 0.f, s3 = 0.f, s4 = 0.f;
#pragma unroll
    for (int kf = 0; kf < 4; ++kf) {
      const float* xp = xg + token * 128 + kf * 32 + q * 8;
      float4 xa = *(const float4*)xp, xb = *(const float4*)(xp + 4);
      const float* p1 = cb + (size_t)ca * 128 + kf * 32 + q * 8;
      float4 ua = *(const float4*)p1, ub = *(const float4*)(p1 + 4);
      const float* p2 = cb + (size_t)cb2 * 128 + kf * 32 + q * 8;
      float4 va = *(const float4*)p2, vb = *(const float4*)(p2 + 4);
      const float* p3 = cb + (size_t)cc * 128 + kf * 32 + q * 8;
      float4 wa = *(const float4*)p3, wb = *(const float4*)(p3 + 4);
      const float* p4 = cb + (size_t)cd * 128 + kf * 32 + q * 8;
      float4 ya = *(const float4*)p4, yb = *(const float4*)(p4 + 4);
      float xv[8] = {xa.x, xa.y, xa.z, xa.w, xb.x, xb.y, xb.z, xb.w};
      float e1[8] = {ua.x, ua.y, ua.z, ua.w, ub.x, ub.y, ub.z, ub.w};
      float e2[8] = {va.x, va.y, va.z, va.w, vb.x, vb.y, vb.z, vb.w};
      float e3[8] = {wa.x, wa.y, wa.z, wa.w, wb.x, wb.y, wb.z, wb.w};
      float e4[8] = {ya.x, ya.y, ya.z, ya.w, yb.x, yb.y, yb.z, yb.w};
#pragma unroll
      for (int j = 0; j < 8; ++j) {
        float f1 = xv[j] - e1[j];
        float f2 = xv[j] - e2[j];
        float f3 = xv[j] - e3[j];
        float f4 = xv[j] - e4[j];
        s1 = fmaf(f1, f1, s1);
        s2 = fmaf(f2, f2, s2);
        s3 = fmaf(f3, f3, s3);
        s4 = fmaf(f4, f4, s4);
      }
    }
    s1 += __shfl_xor(s1, 16); s1 += __shfl_xor(s1, 32);
    s2 += __shfl_xor(s2, 16); s2 += __shfl_xor(s2, 32);
    s3 += __shfl_xor(s3, 16); s3 += __shfl_xor(s3, 32);
    s4 += __shfl_xor(s4, 16); s4 += __shfl_xor(s4, 32);
    // pick min distance, ties -> lowest index (argmin-first semantics)
    float bs = s1; int bk = ca;
    bool u2 = (s2 < bs) || (s2 == bs && cb2 < bk); bs = u2 ? s2 : bs; bk = u2 ? cb2 : bk;
    bool u3 = (s3 < bs) || (s3 == bs && cc < bk);  bs = u3 ? s3 : bs; bk = u3 ? cc : bk;
    bool u4 = (s4 < bs) || (s4 == bs && cd < bk);  bs = u4 ? s4 : bs; bk = u4 ? cd : bk;
#pragma unroll
    for (int kf = 0; kf < 4; ++kf) {
      const float* pw = cb + (size_t)bk * 128 + kf * 32 + q * 8;
      float4 wa = *(const float4*)pw, wb = *(const float4*)(pw + 4);
      float* op = xq + token * 128 + kf * 32 + q * 8;
      *(float4*)op = wa;
      *(float4*)(op + 4) = wb;
    }
    if (q == 0) lacc += bs;
  }
#pragma unroll
  for (int off = 1; off < 64; off <<= 1) lacc += __shfl_xor(lacc, off);
  if (lane == 0) sLoss[wave] = lacc;
  __syncthreads();
  // block fully owns loss[blockIdx.x] (128 tokens = one (b,s) slice)
  if (tid == 0) {
    float s = 0.f;
#pragma unroll
    for (int w = 0; w < 8; ++w) s += sLoss[w];
    loss[blockIdx.x] = s * (1.25f / 16384.f);
  }
}

// ---------------------------------------------------------------------------
extern "C" void kernel_launch(void* const* d_in, const int* in_sizes, int n_in,
                              void* d_out, int out_size, void* d_ws, size_t ws_size,
                              hipStream_t stream) {
  const float* x = (const float*)d_in[0];   // [8,64,128,128] fp32
  const float* cb = (const float*)d_in[1];  // [1024,128] fp32
  float* out = (float*)d_out;
  float* xq = out;
  float* loss = out + (size_t)8 * 64 * 128 * 128;  // 512 floats

  // ws: cbimg (hi-only, row-major) 256 KB | cbn 4 KB
  unsigned short* cbimg = (unsigned short*)d_ws;
  float* cbn = (float*)(cbimg + (size_t)1024 * 128);

  vq_convert_cb<<<16, 64, 0, stream>>>(cb, cbimg, cbn);
  vq_main<<<512, 512, 0, stream>>>(x, cb, cbimg, cbn, xq, loss);
}